// Round 3
// baseline (244.510 us; speedup 1.0000x reference)
//
#include <hip/hip_runtime.h>
#include <hip/hip_bf16.h>
#include <math.h>

typedef __attribute__((ext_vector_type(8))) __bf16 bf16x8;
typedef __attribute__((ext_vector_type(4))) float f32x4;

#define DIM 1024
#define SEQ 2048
#define BATCH 4
#define ROWS (BATCH*SEQ)

#define BAR() do { asm volatile("" ::: "memory"); __builtin_amdgcn_s_barrier(); asm volatile("" ::: "memory"); } while(0)
#define WAITV(n) asm volatile("s_waitcnt vmcnt(" #n ")" ::: "memory")
#define SCHED0() __builtin_amdgcn_sched_barrier(0)

__device__ __forceinline__ unsigned short f2bf(float f) {
  unsigned int u = __float_as_uint(f);
  u += 0x7FFF + ((u >> 16) & 1);   // RNE
  return (unsigned short)(u >> 16);
}
__device__ __forceinline__ unsigned short to_bf_bits(float v) { return f2bf(v); }
__device__ __forceinline__ unsigned short to_bf_bits(unsigned short v) { return v; }

__device__ __forceinline__ void gload_lds16(const void* g, void* lds) {
  __builtin_amdgcn_global_load_lds((__attribute__((address_space(1))) void*)g,
                                   (__attribute__((address_space(3))) void*)lds,
                                   16, 0, 0);
}

// ---------- f32 -> bf16 ----------
__global__ __launch_bounds__(256)
void conv_f32_bf16(const float* __restrict__ src, unsigned short* __restrict__ dst, int n8) {
  int i = blockIdx.x * blockDim.x + threadIdx.x;
  if (i >= n8) return;
  const float4* s = reinterpret_cast<const float4*>(src) + (size_t)i * 2;
  float4 a = s[0], b = s[1];
  union { unsigned short h[8]; uint4 v; } p;
  p.h[0]=f2bf(a.x); p.h[1]=f2bf(a.y); p.h[2]=f2bf(a.z); p.h[3]=f2bf(a.w);
  p.h[4]=f2bf(b.x); p.h[5]=f2bf(b.y); p.h[6]=f2bf(b.z); p.h[7]=f2bf(b.w);
  reinterpret_cast<uint4*>(dst)[i] = p.v;
}

// ---------- transpose+convert: src[R][C] -> dst[C][R] bf16, batched via z ----------
template<typename Tin>
__global__ __launch_bounds__(1024)
void transpose_conv(const Tin* __restrict__ src, int ldsrc, size_t sstride,
                    unsigned short* __restrict__ dst, int lddst, size_t dstride) {
  __shared__ unsigned short tile[32][33];
  const Tin* s = src + (size_t)blockIdx.z * sstride;
  unsigned short* d = dst + (size_t)blockIdx.z * dstride;
  int tx = threadIdx.x, ty = threadIdx.y;
  int r = blockIdx.y * 32 + ty, c = blockIdx.x * 32 + tx;
  tile[ty][tx] = to_bf_bits(s[(size_t)r * ldsrc + c]);
  __syncthreads();
  d[(size_t)(blockIdx.x * 32 + ty) * lddst + blockIdx.y * 32 + tx] = tile[tx][ty];
}

// quadrant MFMA: acc[MB..MB+3][NBASE..NBASE+NLO-1] += af x bg (all indices static)
template<int NREP, int NLO, int MB, int NBASE>
__device__ __forceinline__ void quad(f32x4 (&acc)[8][NREP], const bf16x8 (&af)[4][2],
                                     const bf16x8 (&bg)[NLO][2]) {
#pragma unroll
  for (int kk = 0; kk < 2; ++kk)
#pragma unroll
    for (int m = 0; m < 4; ++m)
#pragma unroll
      for (int n = 0; n < NLO; ++n)
        acc[MB + m][NBASE + n] =
            __builtin_amdgcn_mfma_f32_16x16x32_bf16(af[m][kk], bg[n][kk], acc[MB + m][NBASE + n], 0, 0, 0);
}

// ---------- phase-pipelined NT GEMM: C[M,N] = A[M,K]*B[N,K]^T ----------
// BM=256, BK=64, 8 waves (2Mx4N), per-wave 128 x (BN/4).
// LDS double buffer (2 K-tiles). 4 phases per K-tile, each:
//   {ds_read quadrant frags | stage one half-tile of future tile} -> BAR ->
//   setprio(1) + quadrant MFMA + setprio(0) -> BAR.
// Counted vmcnt(2) once per tile (never 0 mid-loop). XOR-swizzled 16B slots
// (8 slots per 128B row), pre-swizzled global source for linear gload_lds dest.
#define EPI_QKV 0
#define EPI_F32 1
#define EPI_BF16 2
#define EPI_BIAS_F32 3

template<int BN, int EPI>
__global__ __launch_bounds__(512, 2)
void gemm8(const unsigned short* __restrict__ A, int lda, size_t sA,
           const unsigned short* __restrict__ B, int ldb, size_t sB,
           void* __restrict__ C, int ldc, size_t sC,
           const float* __restrict__ bias, int K) {
  constexpr int NREP = BN / 64;     // 4 or 2 (16-col frags per wave)
  constexpr int NLO = NREP / 2;     // 2 or 1
  constexpr int NW = 16 * NREP;     // per-wave col width: 64 or 32
  __shared__ unsigned short As[2 * 256 * 64];
  __shared__ unsigned short Bs[2 * BN * 64];

  const int tid = threadIdx.x;
  const int lane = tid & 63, wave = tid >> 6;
  const int wm = wave >> 2, wn = wave & 3;
  const int fr = lane & 15, fk = lane >> 4;
  const int tileM = blockIdx.y * 256, tileN = blockIdx.x * BN;
  const unsigned short* Ab = A + (size_t)blockIdx.z * sA;
  const unsigned short* Bb = B + (size_t)blockIdx.z * sB;

  // staging: one round = 512 thr * 16B = 8KB = 64 rows of 128B (linear LDS dest)
  const int srow = tid >> 3;                 // row within round (0..63)
  const int sg = (tid & 7) ^ (srow & 7);     // pre-swizzled source 16B-chunk

  auto stageA = [&](int buf, int half, int k0) {
#pragma unroll
    for (int q = 0; q < 2; ++q) {
      int rl = half * 128 + q * 64 + srow;
      gload_lds16(Ab + (size_t)(tileM + rl) * lda + k0 + sg * 8,
                  &As[buf * (256 * 64) + (half * 128 + q * 64) * 64 + tid * 8]);
    }
  };
  auto stageB = [&](int buf, int part, int k0) {
#pragma unroll
    for (int q = 0; q < 2; ++q) {
      int rl = part * 128 + q * 64 + srow;
      gload_lds16(Bb + (size_t)(tileN + rl) * ldb + k0 + sg * 8,
                  &Bs[buf * (BN * 64) + (part * 128 + q * 64) * 64 + tid * 8]);
    }
  };

  f32x4 acc[8][NREP];
#pragma unroll
  for (int m = 0; m < 8; ++m)
#pragma unroll
    for (int n = 0; n < NREP; ++n) acc[m][n] = (f32x4){0.f, 0.f, 0.f, 0.f};

  const int NS = K >> 6;   // K-tiles of 64
  // prologue: tile0 fully + tile1.A0 (order matters for vmcnt accounting)
  stageA(0, 0, 0); stageA(0, 1, 0); stageB(0, 0, 0);
  if (BN == 256) stageB(0, 1, 0);
  stageA(1, 0, 64);

  bf16x8 afLo[4][2], afHi[4][2], bgLo[NLO][2], bgHi[NLO][2];

  for (int t = 0; t < NS; ++t) {
    const int cb = t & 1, nb = cb ^ 1;
    const unsigned short* Asl = &As[cb * (256 * 64)];
    const unsigned short* Bsl = &Bs[cb * (BN * 64)];
    const int k1 = (t + 1) << 6, k2 = (t + 2) << 6;

    // ---- P0: afLo + bgLo | stage (t+1).A1 | Q0 = m0-3 x nLo ----
    if (t + 1 < NS) { WAITV(2); } else { WAITV(0); }
    BAR();
#pragma unroll
    for (int m = 0; m < 4; ++m) {
      int rl = wm * 128 + m * 16 + fr;
#pragma unroll
      for (int kk = 0; kk < 2; ++kk)
        afLo[m][kk] = *(const bf16x8*)&Asl[rl * 64 + (((kk * 4 + fk) ^ (rl & 7)) << 3)];
    }
#pragma unroll
    for (int n = 0; n < NLO; ++n) {
      int rl = wn * NW + n * 16 + fr;
#pragma unroll
      for (int kk = 0; kk < 2; ++kk)
        bgLo[n][kk] = *(const bf16x8*)&Bsl[rl * 64 + (((kk * 4 + fk) ^ (rl & 7)) << 3)];
    }
    if (t + 1 < NS) stageA(nb, 1, k1);
    BAR(); SCHED0();
    __builtin_amdgcn_s_setprio(1);
    quad<NREP, NLO, 0, 0>(acc, afLo, bgLo);
    __builtin_amdgcn_s_setprio(0); SCHED0();
    BAR();

    // ---- P1: bgHi | stage (t+1).B0 | Q1 = m0-3 x nHi ----
#pragma unroll
    for (int n = 0; n < NLO; ++n) {
      int rl = wn * NW + (NLO + n) * 16 + fr;
#pragma unroll
      for (int kk = 0; kk < 2; ++kk)
        bgHi[n][kk] = *(const bf16x8*)&Bsl[rl * 64 + (((kk * 4 + fk) ^ (rl & 7)) << 3)];
    }
    if (t + 1 < NS) stageB(nb, 0, k1);
    BAR(); SCHED0();
    __builtin_amdgcn_s_setprio(1);
    quad<NREP, NLO, 0, NLO>(acc, afLo, bgHi);
    __builtin_amdgcn_s_setprio(0); SCHED0();
    BAR();

    // ---- P2: afHi | stage (t+1).B1 (BN=256) | Q2 = m4-7 x nLo ----
#pragma unroll
    for (int m = 0; m < 4; ++m) {
      int rl = wm * 128 + (4 + m) * 16 + fr;
#pragma unroll
      for (int kk = 0; kk < 2; ++kk)
        afHi[m][kk] = *(const bf16x8*)&Asl[rl * 64 + (((kk * 4 + fk) ^ (rl & 7)) << 3)];
    }
    if (BN == 256) { if (t + 1 < NS) stageB(nb, 1, k1); }
    BAR(); SCHED0();
    __builtin_amdgcn_s_setprio(1);
    quad<NREP, NLO, 4, 0>(acc, afHi, bgLo);
    __builtin_amdgcn_s_setprio(0); SCHED0();
    BAR();

    // ---- P3: stage (t+2).A0 | Q3 = m4-7 x nHi ----
    if (t + 2 < NS) stageA(cb, 0, k2);
    BAR(); SCHED0();
    __builtin_amdgcn_s_setprio(1);
    quad<NREP, NLO, 4, NLO>(acc, afHi, bgHi);
    __builtin_amdgcn_s_setprio(0); SCHED0();
    BAR();
  }

#pragma unroll
  for (int m = 0; m < 8; ++m)
#pragma unroll
    for (int n = 0; n < NREP; ++n)
#pragma unroll
      for (int j = 0; j < 4; ++j) {
        int row = tileM + wm * 128 + m * 16 + fk * 4 + j;
        int col = tileN + wn * NW + n * 16 + fr;
        float v = acc[m][n][j];
        if (EPI == EPI_QKV) {
          v += bias[col];
          if (col < DIM) v *= 0.03125f;   // 1/sqrt(1024)
          ((unsigned short*)C + (size_t)blockIdx.z * sC)[(size_t)row * ldc + col] = f2bf(v);
        } else if (EPI == EPI_BF16) {
          ((unsigned short*)C + (size_t)blockIdx.z * sC)[(size_t)row * ldc + col] = f2bf(v);
        } else if (EPI == EPI_BIAS_F32) {
          ((float*)C + (size_t)blockIdx.z * sC)[(size_t)row * ldc + col] = v + bias[col];
        } else {
          ((float*)C + (size_t)blockIdx.z * sC)[(size_t)row * ldc + col] = v;
        }
      }
}

// ---------- row softmax, in-place: fp32 row -> bf16 P at row start ----------
__global__ __launch_bounds__(256)
void softmax_kernel(float* __restrict__ S, size_t zstride) {
  __shared__ float red[8];
  float* row = S + (size_t)blockIdx.y * zstride + (size_t)blockIdx.x * SEQ;
  const int tid = threadIdx.x;
  const int lane = tid & 63, wave = tid >> 6;
  const float4* src = reinterpret_cast<const float4*>(row) + tid * 2;
  float4 a = src[0], b = src[1];
  float v[8] = {a.x, a.y, a.z, a.w, b.x, b.y, b.z, b.w};
  float m = v[0];
#pragma unroll
  for (int i = 1; i < 8; ++i) m = fmaxf(m, v[i]);
  for (int o = 32; o; o >>= 1) m = fmaxf(m, __shfl_xor(m, o));
  if (lane == 0) red[wave] = m;
  __syncthreads();
  m = fmaxf(fmaxf(red[0], red[1]), fmaxf(red[2], red[3]));
  float e[8], s = 0.f;
#pragma unroll
  for (int i = 0; i < 8; ++i) { e[i] = expf(v[i] - m); s += e[i]; }
  for (int o = 32; o; o >>= 1) s += __shfl_xor(s, o);
  if (lane == 0) red[4 + wave] = s;
  __syncthreads();
  s = red[4] + red[5] + red[6] + red[7];
  float inv = 1.f / s;
  union { unsigned short h[8]; uint4 u; } p;
#pragma unroll
  for (int i = 0; i < 8; ++i) p.h[i] = f2bf(e[i] * inv);
  reinterpret_cast<uint4*>(row)[tid] = p.u;
}

extern "C" void kernel_launch(void* const* d_in, const int* in_sizes, int n_in,
                              void* d_out, int out_size, void* d_ws, size_t ws_size,
                              hipStream_t stream) {
  const float* X     = (const float*)d_in[0];
  const float* W_in  = (const float*)d_in[1];
  const float* b_in  = (const float*)d_in[2];
  const float* W_out = (const float*)d_in[3];
  const float* b_out = (const float*)d_in[4];
  float* out = (float*)d_out;
  char* ws = (char*)d_ws;

  size_t o = 0;
  auto alloc = [&](size_t bytes) { size_t r = o; o += (bytes + 255) & ~(size_t)255; return r; };
  unsigned short* Xbf   = (unsigned short*)(ws + alloc((size_t)ROWS * DIM * 2));     // aliased as O later
  unsigned short* WinT  = (unsigned short*)(ws + alloc((size_t)3 * DIM * DIM * 2));
  unsigned short* WoutT = (unsigned short*)(ws + alloc((size_t)DIM * DIM * 2));
  unsigned short* QKV   = (unsigned short*)(ws + alloc((size_t)ROWS * 3 * DIM * 2));
  size_t fixed = o;
  size_t per_batch = (((size_t)SEQ * SEQ * 4 + 255) & ~(size_t)255) +
                     (((size_t)DIM * SEQ * 2 + 255) & ~(size_t)255);
  int G = (ws_size >= fixed + 4 * per_batch) ? BATCH : 1;
  float*          Sc = (float*)(ws + alloc((size_t)G * SEQ * SEQ * 4));  // P written in place (bf16)
  unsigned short* Vt = (unsigned short*)(ws + alloc((size_t)G * DIM * SEQ * 2));
  unsigned short* O  = Xbf;   // Xbf dead after QKV GEMM

  conv_f32_bf16<<<(ROWS * DIM / 8 + 255) / 256, 256, 0, stream>>>(X, Xbf, ROWS * DIM / 8);
  transpose_conv<float><<<dim3(3 * DIM / 32, DIM / 32, 1), dim3(32, 32), 0, stream>>>(
      W_in, 3 * DIM, 0, WinT, DIM, 0);
  transpose_conv<float><<<dim3(DIM / 32, DIM / 32, 1), dim3(32, 32), 0, stream>>>(
      W_out, DIM, 0, WoutT, DIM, 0);
  gemm8<256, EPI_QKV><<<dim3(3 * DIM / 256, ROWS / 256, 1), 512, 0, stream>>>(
      Xbf, DIM, 0, WinT, DIM, 0, QKV, 3 * DIM, 0, b_in, DIM);

  for (int b0 = 0; b0 < BATCH; b0 += G) {
    const unsigned short* Qb = QKV + (size_t)b0 * SEQ * 3 * DIM;
    const unsigned short* Kb = Qb + DIM;
    const unsigned short* Vb = Qb + 2 * DIM;
    transpose_conv<unsigned short><<<dim3(DIM / 32, SEQ / 32, G), dim3(32, 32), 0, stream>>>(
        Vb, 3 * DIM, (size_t)SEQ * 3 * DIM, Vt, SEQ, (size_t)DIM * SEQ);
    gemm8<256, EPI_F32><<<dim3(SEQ / 256, SEQ / 256, G), 512, 0, stream>>>(
        Qb, 3 * DIM, (size_t)SEQ * 3 * DIM, Kb, 3 * DIM, (size_t)SEQ * 3 * DIM,
        Sc, SEQ, (size_t)SEQ * SEQ, nullptr, DIM);
    softmax_kernel<<<dim3(SEQ, G), 256, 0, stream>>>(Sc, (size_t)SEQ * SEQ);
    gemm8<128, EPI_BF16><<<dim3(DIM / 128, SEQ / 256, G), 512, 0, stream>>>(
        (const unsigned short*)Sc, 2 * SEQ, (size_t)2 * SEQ * SEQ,
        Vt, SEQ, (size_t)DIM * SEQ,
        O + (size_t)b0 * SEQ * DIM, DIM, (size_t)SEQ * DIM, nullptr, SEQ);
  }
  gemm8<128, EPI_BIAS_F32><<<dim3(DIM / 128, ROWS / 256, 1), 512, 0, stream>>>(
      O, DIM, 0, WoutT, DIM, 0, out, DIM, 0, b_out, DIM);
}

// Round 4
// 230.437 us; speedup vs baseline: 1.0611x; 1.0611x over previous
//
#include <hip/hip_runtime.h>
#include <hip/hip_bf16.h>
#include <math.h>

typedef __attribute__((ext_vector_type(8))) __bf16 bf16x8;
typedef __attribute__((ext_vector_type(4))) float f32x4;
typedef __attribute__((ext_vector_type(4))) unsigned int u32x4;

#define DIM 1024
#define SEQ 2048
#define BATCH 4
#define ROWS (BATCH*SEQ)

#define BAR() do { asm volatile("" ::: "memory"); __builtin_amdgcn_s_barrier(); asm volatile("" ::: "memory"); } while(0)
#define WAITV(n) asm volatile("s_waitcnt vmcnt(" #n ")" ::: "memory")
#define WAITL0() asm volatile("s_waitcnt lgkmcnt(0)" ::: "memory")
#define SCHED0() __builtin_amdgcn_sched_barrier(0)
#define PRIO(x) __builtin_amdgcn_s_setprio(x)

// inline-asm LDS read: escapes SIInsertWaitcnts' conservative vmcnt(0)-before-
// ds_read (LDS-DMA alias) — we order against global_load_lds manually via WAITV.
#define DSR(d, a, off) do { u32x4 _t; \
  asm volatile("ds_read_b128 %0, %1 offset:" #off : "=v"(_t) : "v"(a)); \
  (d) = __builtin_bit_cast(bf16x8, _t); } while(0)

__device__ __forceinline__ unsigned short f2bf(float f) {
  unsigned int u = __float_as_uint(f);
  u += 0x7FFF + ((u >> 16) & 1);   // RNE
  return (unsigned short)(u >> 16);
}
__device__ __forceinline__ unsigned short to_bf_bits(float v) { return f2bf(v); }
__device__ __forceinline__ unsigned short to_bf_bits(unsigned short v) { return v; }

__device__ __forceinline__ void gload_lds16(const void* g, void* lds) {
  __builtin_amdgcn_global_load_lds((__attribute__((address_space(1))) void*)g,
                                   (__attribute__((address_space(3))) void*)lds,
                                   16, 0, 0);
}

// ---------- f32 -> bf16 ----------
__global__ __launch_bounds__(256)
void conv_f32_bf16(const float* __restrict__ src, unsigned short* __restrict__ dst, int n8) {
  int i = blockIdx.x * blockDim.x + threadIdx.x;
  if (i >= n8) return;
  const float4* s = reinterpret_cast<const float4*>(src) + (size_t)i * 2;
  float4 a = s[0], b = s[1];
  union { unsigned short h[8]; uint4 v; } p;
  p.h[0]=f2bf(a.x); p.h[1]=f2bf(a.y); p.h[2]=f2bf(a.z); p.h[3]=f2bf(a.w);
  p.h[4]=f2bf(b.x); p.h[5]=f2bf(b.y); p.h[6]=f2bf(b.z); p.h[7]=f2bf(b.w);
  reinterpret_cast<uint4*>(dst)[i] = p.v;
}

// ---------- transpose+convert: src[R][C] -> dst[C][R] bf16, batched via z ----------
template<typename Tin>
__global__ __launch_bounds__(1024)
void transpose_conv(const Tin* __restrict__ src, int ldsrc, size_t sstride,
                    unsigned short* __restrict__ dst, int lddst, size_t dstride) {
  __shared__ unsigned short tile[32][33];
  const Tin* s = src + (size_t)blockIdx.z * sstride;
  unsigned short* d = dst + (size_t)blockIdx.z * dstride;
  int tx = threadIdx.x, ty = threadIdx.y;
  int r = blockIdx.y * 32 + ty, c = blockIdx.x * 32 + tx;
  tile[ty][tx] = to_bf_bits(s[(size_t)r * ldsrc + c]);
  __syncthreads();
  d[(size_t)(blockIdx.x * 32 + ty) * lddst + blockIdx.y * 32 + tx] = tile[tx][ty];
}

// ---------- phase-pipelined NT GEMM: C[M,N] = A[M,K]*B[N,K]^T ----------
// BM=256, BK=64, 8 waves (2M x 4N), per-wave 128 x (BN/4).
// LDS double buffer. BN=256: 4 phases/K-tile; BN=128: 2 phases/K-tile.
// Each phase: {asm ds_read frags | issue global_load_lds} -> BAR ->
//   lgkmcnt(0) -> sched_barrier -> setprio(1) + 16 MFMA + setprio(0).
// Counted vmcnt(2) once per K-tile, placed before the tile's closing barrier.
#define EPI_QKV 0
#define EPI_F32 1
#define EPI_BF16 2
#define EPI_BIAS_F32 3

template<int BN, int EPI>
__global__ __launch_bounds__(512, 2)
void gemm8(const unsigned short* __restrict__ A, int lda, size_t sA,
           const unsigned short* __restrict__ B, int ldb, size_t sB,
           void* __restrict__ C, int ldc, size_t sC,
           const float* __restrict__ bias, int K) {
  constexpr int NREP = BN / 64;     // 4 or 2
  constexpr int NW = 16 * NREP;     // 64 or 32
  __shared__ unsigned short As[2 * 256 * 64];
  __shared__ unsigned short Bs[2 * BN * 64];

  const int tid = threadIdx.x;
  const int lane = tid & 63, wave = tid >> 6;
  const int wm = wave >> 2, wn = wave & 3;
  const int fr = lane & 15, fk = lane >> 4;
  const int tileM = blockIdx.y * 256, tileN = blockIdx.x * BN;
  const unsigned short* Ab = A + (size_t)blockIdx.z * sA;
  const unsigned short* Bb = B + (size_t)blockIdx.z * sB;

  // staging: one call = 2 rounds x 512 thr x 16B = 128 rows of 128B, linear LDS dest
  const int srow = tid >> 3;
  const int sg = (tid & 7) ^ (srow & 7);     // pre-swizzled source 16B-chunk

  auto stageA = [&](int buf, int half, int k0) {
#pragma unroll
    for (int q = 0; q < 2; ++q) {
      int rl = half * 128 + q * 64 + srow;
      gload_lds16(Ab + (size_t)(tileM + rl) * lda + k0 + sg * 8,
                  &As[buf * (256 * 64) + (half * 128 + q * 64) * 64 + tid * 8]);
    }
  };
  auto stageB = [&](int buf, int part, int k0) {
#pragma unroll
    for (int q = 0; q < 2; ++q) {
      int rl = part * 128 + q * 64 + srow;
      gload_lds16(Bb + (size_t)(tileN + rl) * ldb + k0 + sg * 8,
                  &Bs[buf * (BN * 64) + (part * 128 + q * 64) * 64 + tid * 8]);
    }
  };

  f32x4 acc[8][NREP];
#pragma unroll
  for (int m = 0; m < 8; ++m)
#pragma unroll
    for (int n = 0; n < NREP; ++n) acc[m][n] = (f32x4){0.f, 0.f, 0.f, 0.f};

  const int NS = K >> 6;
  // LDS byte bases + per-lane fragment offsets
  const unsigned asb = (unsigned)(size_t)(__attribute__((address_space(3))) unsigned short*)As;
  const unsigned bsb = (unsigned)(size_t)(__attribute__((address_space(3))) unsigned short*)Bs;
  const unsigned aoff = (unsigned)((wm * 128 + fr) * 128 + ((fk ^ (fr & 7)) << 4));
  const unsigned boff = (unsigned)((wn * NW + fr) * 128 + ((fk ^ (fr & 7)) << 4));

  // prologue: tile0 fully + tile1.A0 (issue order = vmcnt retire order)
  stageA(0, 0, 0); stageA(0, 1, 0); stageB(0, 0, 0);
  if (BN == 256) stageB(0, 1, 0);
  if (NS > 1) { stageA(1, 0, 64); WAITV(2); } else { WAITV(0); }
  BAR();

  bf16x8 afLo[4][2], afHi[4][2], bg[NREP][2];

  for (int t = 0; t < NS; ++t) {
    const unsigned aA0 = asb + ((t & 1) ? 32768u : 0u) + aoff;
    const unsigned aA1 = aA0 ^ 64u;
    const unsigned bB0 = bsb + ((t & 1) ? (unsigned)(BN * 128) : 0u) + boff;
    const unsigned bB1 = bB0 ^ 64u;
    const int k1 = (t + 1) << 6, k2 = (t + 2) << 6;
    const int nb = (t & 1) ^ 1;

    if constexpr (BN == 256) {
      // ---- P0: afLo + bgLo | stage (t+1).A1 | Q0 ----
      DSR(afLo[0][0], aA0, 0); DSR(afLo[1][0], aA0, 2048); DSR(afLo[2][0], aA0, 4096); DSR(afLo[3][0], aA0, 6144);
      DSR(afLo[0][1], aA1, 0); DSR(afLo[1][1], aA1, 2048); DSR(afLo[2][1], aA1, 4096); DSR(afLo[3][1], aA1, 6144);
      DSR(bg[0][0], bB0, 0); DSR(bg[1][0], bB0, 2048);
      DSR(bg[0][1], bB1, 0); DSR(bg[1][1], bB1, 2048);
      if (t + 1 < NS) stageA(nb, 1, k1);
      BAR(); WAITL0(); SCHED0();
      PRIO(1);
#pragma unroll
      for (int kk = 0; kk < 2; ++kk)
#pragma unroll
        for (int m = 0; m < 4; ++m)
#pragma unroll
          for (int n = 0; n < 2; ++n)
            acc[m][n] = __builtin_amdgcn_mfma_f32_16x16x32_bf16(afLo[m][kk], bg[n][kk], acc[m][n], 0, 0, 0);
      PRIO(0); SCHED0();
      BAR();
      // ---- P1: bgHi | stage (t+1).B0 | Q1 ----
      DSR(bg[2][0], bB0, 4096); DSR(bg[3][0], bB0, 6144);
      DSR(bg[2][1], bB1, 4096); DSR(bg[3][1], bB1, 6144);
      if (t + 1 < NS) stageB(nb, 0, k1);
      BAR(); WAITL0(); SCHED0();
      PRIO(1);
#pragma unroll
      for (int kk = 0; kk < 2; ++kk)
#pragma unroll
        for (int m = 0; m < 4; ++m)
#pragma unroll
          for (int n = 0; n < 2; ++n)
            acc[m][2 + n] = __builtin_amdgcn_mfma_f32_16x16x32_bf16(afLo[m][kk], bg[2 + n][kk], acc[m][2 + n], 0, 0, 0);
      PRIO(0); SCHED0();
      BAR();
      // ---- P2: afHi | stage (t+1).B1 | Q2 ----
      DSR(afHi[0][0], aA0, 8192); DSR(afHi[1][0], aA0, 10240); DSR(afHi[2][0], aA0, 12288); DSR(afHi[3][0], aA0, 14336);
      DSR(afHi[0][1], aA1, 8192); DSR(afHi[1][1], aA1, 10240); DSR(afHi[2][1], aA1, 12288); DSR(afHi[3][1], aA1, 14336);
      if (t + 1 < NS) stageB(nb, 1, k1);
      BAR(); WAITL0(); SCHED0();
      PRIO(1);
#pragma unroll
      for (int kk = 0; kk < 2; ++kk)
#pragma unroll
        for (int m = 0; m < 4; ++m)
#pragma unroll
          for (int n = 0; n < 2; ++n)
            acc[4 + m][n] = __builtin_amdgcn_mfma_f32_16x16x32_bf16(afHi[m][kk], bg[n][kk], acc[4 + m][n], 0, 0, 0);
      PRIO(0); SCHED0();
      BAR();
      // ---- P3: stage (t+2).A0 | Q3 | vmcnt(2) ----
      if (t + 2 < NS) stageA(t & 1, 0, k2);
      BAR();
      PRIO(1);
#pragma unroll
      for (int kk = 0; kk < 2; ++kk)
#pragma unroll
        for (int m = 0; m < 4; ++m)
#pragma unroll
          for (int n = 0; n < 2; ++n)
            acc[4 + m][2 + n] = __builtin_amdgcn_mfma_f32_16x16x32_bf16(afHi[m][kk], bg[2 + n][kk], acc[4 + m][2 + n], 0, 0, 0);
      PRIO(0); SCHED0();
      if (t + 1 < NS) { if (t + 2 < NS) { WAITV(2); } else { WAITV(0); } }
      BAR();
    } else {
      // ---- P0: afLo + bg | stage (t+1).{A1,B0} | Q01 ----
      DSR(afLo[0][0], aA0, 0); DSR(afLo[1][0], aA0, 2048); DSR(afLo[2][0], aA0, 4096); DSR(afLo[3][0], aA0, 6144);
      DSR(afLo[0][1], aA1, 0); DSR(afLo[1][1], aA1, 2048); DSR(afLo[2][1], aA1, 4096); DSR(afLo[3][1], aA1, 6144);
      DSR(bg[0][0], bB0, 0); DSR(bg[1][0], bB0, 2048);
      DSR(bg[0][1], bB1, 0); DSR(bg[1][1], bB1, 2048);
      if (t + 1 < NS) { stageA(nb, 1, k1); stageB(nb, 0, k1); }
      BAR(); WAITL0(); SCHED0();
      PRIO(1);
#pragma unroll
      for (int kk = 0; kk < 2; ++kk)
#pragma unroll
        for (int m = 0; m < 4; ++m)
#pragma unroll
          for (int n = 0; n < 2; ++n)
            acc[m][n] = __builtin_amdgcn_mfma_f32_16x16x32_bf16(afLo[m][kk], bg[n][kk], acc[m][n], 0, 0, 0);
      PRIO(0); SCHED0();
      BAR();
      // ---- P1: afHi | stage (t+2).A0 | Q23 | vmcnt(2) ----
      DSR(afHi[0][0], aA0, 8192); DSR(afHi[1][0], aA0, 10240); DSR(afHi[2][0], aA0, 12288); DSR(afHi[3][0], aA0, 14336);
      DSR(afHi[0][1], aA1, 8192); DSR(afHi[1][1], aA1, 10240); DSR(afHi[2][1], aA1, 12288); DSR(afHi[3][1], aA1, 14336);
      if (t + 2 < NS) stageA(t & 1, 0, k2);
      BAR(); WAITL0(); SCHED0();
      PRIO(1);
#pragma unroll
      for (int kk = 0; kk < 2; ++kk)
#pragma unroll
        for (int m = 0; m < 4; ++m)
#pragma unroll
          for (int n = 0; n < 2; ++n)
            acc[4 + m][n] = __builtin_amdgcn_mfma_f32_16x16x32_bf16(afHi[m][kk], bg[n][kk], acc[4 + m][n], 0, 0, 0);
      PRIO(0); SCHED0();
      if (t + 1 < NS) { if (t + 2 < NS) { WAITV(2); } else { WAITV(0); } }
      BAR();
    }
  }

#pragma unroll
  for (int m = 0; m < 8; ++m)
#pragma unroll
    for (int n = 0; n < NREP; ++n)
#pragma unroll
      for (int j = 0; j < 4; ++j) {
        int row = tileM + wm * 128 + m * 16 + fk * 4 + j;
        int col = tileN + wn * NW + n * 16 + fr;
        float v = acc[m][n][j];
        if (EPI == EPI_QKV) {
          v += bias[col];
          if (col < DIM) v *= 0.03125f;   // 1/sqrt(1024)
          ((unsigned short*)C + (size_t)blockIdx.z * sC)[(size_t)row * ldc + col] = f2bf(v);
        } else if (EPI == EPI_BF16) {
          ((unsigned short*)C + (size_t)blockIdx.z * sC)[(size_t)row * ldc + col] = f2bf(v);
        } else if (EPI == EPI_BIAS_F32) {
          ((float*)C + (size_t)blockIdx.z * sC)[(size_t)row * ldc + col] = v + bias[col];
        } else {
          ((float*)C + (size_t)blockIdx.z * sC)[(size_t)row * ldc + col] = v;
        }
      }
}

// ---------- row softmax, in-place: fp32 row -> bf16 P at row start ----------
__global__ __launch_bounds__(256)
void softmax_kernel(float* __restrict__ S, size_t zstride) {
  __shared__ float red[8];
  float* row = S + (size_t)blockIdx.y * zstride + (size_t)blockIdx.x * SEQ;
  const int tid = threadIdx.x;
  const int lane = tid & 63, wave = tid >> 6;
  const float4* src = reinterpret_cast<const float4*>(row) + tid * 2;
  float4 a = src[0], b = src[1];
  float v[8] = {a.x, a.y, a.z, a.w, b.x, b.y, b.z, b.w};
  float m = v[0];
#pragma unroll
  for (int i = 1; i < 8; ++i) m = fmaxf(m, v[i]);
  for (int o = 32; o; o >>= 1) m = fmaxf(m, __shfl_xor(m, o));
  if (lane == 0) red[wave] = m;
  __syncthreads();
  m = fmaxf(fmaxf(red[0], red[1]), fmaxf(red[2], red[3]));
  float e[8], s = 0.f;
#pragma unroll
  for (int i = 0; i < 8; ++i) { e[i] = expf(v[i] - m); s += e[i]; }
  for (int o = 32; o; o >>= 1) s += __shfl_xor(s, o);
  if (lane == 0) red[4 + wave] = s;
  __syncthreads();
  s = red[4] + red[5] + red[6] + red[7];
  float inv = 1.f / s;
  union { unsigned short h[8]; uint4 u; } p;
#pragma unroll
  for (int i = 0; i < 8; ++i) p.h[i] = f2bf(e[i] * inv);
  reinterpret_cast<uint4*>(row)[tid] = p.u;
}

extern "C" void kernel_launch(void* const* d_in, const int* in_sizes, int n_in,
                              void* d_out, int out_size, void* d_ws, size_t ws_size,
                              hipStream_t stream) {
  const float* X     = (const float*)d_in[0];
  const float* W_in  = (const float*)d_in[1];
  const float* b_in  = (const float*)d_in[2];
  const float* W_out = (const float*)d_in[3];
  const float* b_out = (const float*)d_in[4];
  float* out = (float*)d_out;
  char* ws = (char*)d_ws;

  size_t o = 0;
  auto alloc = [&](size_t bytes) { size_t r = o; o += (bytes + 255) & ~(size_t)255; return r; };
  unsigned short* Xbf   = (unsigned short*)(ws + alloc((size_t)ROWS * DIM * 2));     // aliased as O later
  unsigned short* WinT  = (unsigned short*)(ws + alloc((size_t)3 * DIM * DIM * 2));
  unsigned short* WoutT = (unsigned short*)(ws + alloc((size_t)DIM * DIM * 2));
  unsigned short* QKV   = (unsigned short*)(ws + alloc((size_t)ROWS * 3 * DIM * 2));
  size_t fixed = o;
  size_t per_batch = (((size_t)SEQ * SEQ * 4 + 255) & ~(size_t)255) +
                     (((size_t)DIM * SEQ * 2 + 255) & ~(size_t)255);
  int G = (ws_size >= fixed + 4 * per_batch) ? BATCH : 1;
  float*          Sc = (float*)(ws + alloc((size_t)G * SEQ * SEQ * 4));  // P written in place (bf16)
  unsigned short* Vt = (unsigned short*)(ws + alloc((size_t)G * DIM * SEQ * 2));
  unsigned short* O  = Xbf;   // Xbf dead after QKV GEMM

  conv_f32_bf16<<<(ROWS * DIM / 8 + 255) / 256, 256, 0, stream>>>(X, Xbf, ROWS * DIM / 8);
  transpose_conv<float><<<dim3(3 * DIM / 32, DIM / 32, 1), dim3(32, 32), 0, stream>>>(
      W_in, 3 * DIM, 0, WinT, DIM, 0);
  transpose_conv<float><<<dim3(DIM / 32, DIM / 32, 1), dim3(32, 32), 0, stream>>>(
      W_out, DIM, 0, WoutT, DIM, 0);
  // QKV: BN=128 -> grid 24x32 = 768 = exactly 3 rounds of 256 CUs
  gemm8<128, EPI_QKV><<<dim3(3 * DIM / 128, ROWS / 256, 1), 512, 0, stream>>>(
      Xbf, DIM, 0, WinT, DIM, 0, QKV, 3 * DIM, 0, b_in, DIM);

  for (int b0 = 0; b0 < BATCH; b0 += G) {
    const unsigned short* Qb = QKV + (size_t)b0 * SEQ * 3 * DIM;
    const unsigned short* Kb = Qb + DIM;
    const unsigned short* Vb = Qb + 2 * DIM;
    transpose_conv<unsigned short><<<dim3(DIM / 32, SEQ / 32, G), dim3(32, 32), 0, stream>>>(
        Vb, 3 * DIM, (size_t)SEQ * 3 * DIM, Vt, SEQ, (size_t)DIM * SEQ);
    gemm8<256, EPI_F32><<<dim3(SEQ / 256, SEQ / 256, G), 512, 0, stream>>>(
        Qb, 3 * DIM, (size_t)SEQ * 3 * DIM, Kb, 3 * DIM, (size_t)SEQ * 3 * DIM,
        Sc, SEQ, (size_t)SEQ * SEQ, nullptr, DIM);
    softmax_kernel<<<dim3(SEQ, G), 256, 0, stream>>>(Sc, (size_t)SEQ * SEQ);
    gemm8<128, EPI_BF16><<<dim3(DIM / 128, SEQ / 256, G), 512, 0, stream>>>(
        (const unsigned short*)Sc, 2 * SEQ, (size_t)2 * SEQ * SEQ,
        Vt, SEQ, (size_t)DIM * SEQ,
        O + (size_t)b0 * SEQ * DIM, DIM, (size_t)SEQ * DIM, nullptr, SEQ);
  }
  gemm8<128, EPI_BIAS_F32><<<dim3(DIM / 128, ROWS / 256, 1), 512, 0, stream>>>(
      O, DIM, 0, WoutT, DIM, 0, out, DIM, 0, b_out, DIM);
}

// Round 5
// 229.514 us; speedup vs baseline: 1.0653x; 1.0040x over previous
//
#include <hip/hip_runtime.h>
#include <hip/hip_bf16.h>
#include <math.h>

typedef __attribute__((ext_vector_type(8))) __bf16 bf16x8;
typedef __attribute__((ext_vector_type(4))) float f32x4;
typedef __attribute__((ext_vector_type(4))) unsigned int u32x4;

#define DIM 1024
#define SEQ 2048
#define BATCH 4
#define ROWS (BATCH*SEQ)

#define BAR() do { asm volatile("" ::: "memory"); __builtin_amdgcn_s_barrier(); asm volatile("" ::: "memory"); } while(0)
#define WAITV(n) asm volatile("s_waitcnt vmcnt(" #n ")" ::: "memory")
#define WAITL0() asm volatile("s_waitcnt lgkmcnt(0)" ::: "memory")
#define SCHED0() __builtin_amdgcn_sched_barrier(0)
#define PRIO(x) __builtin_amdgcn_s_setprio(x)

// inline-asm LDS read: escapes auto-waitcnt; ordered manually via WAITV/WAITL0.
#define DSR(d, a, off) do { u32x4 _t; \
  asm volatile("ds_read_b128 %0, %1 offset:" #off : "=v"(_t) : "v"(a)); \
  (d) = __builtin_bit_cast(bf16x8, _t); } while(0)

__device__ __forceinline__ unsigned short f2bf(float f) {
  unsigned int u = __float_as_uint(f);
  u += 0x7FFF + ((u >> 16) & 1);   // RNE
  return (unsigned short)(u >> 16);
}
__device__ __forceinline__ unsigned short to_bf_bits(float v) { return f2bf(v); }
__device__ __forceinline__ unsigned short to_bf_bits(unsigned short v) { return v; }

__device__ __forceinline__ void gload_lds16(const void* g, void* lds) {
  __builtin_amdgcn_global_load_lds((__attribute__((address_space(1))) void*)g,
                                   (__attribute__((address_space(3))) void*)lds,
                                   16, 0, 0);
}

// ---------- f32 -> bf16 ----------
__global__ __launch_bounds__(256)
void conv_f32_bf16(const float* __restrict__ src, unsigned short* __restrict__ dst, int n8) {
  int i = blockIdx.x * blockDim.x + threadIdx.x;
  if (i >= n8) return;
  const float4* s = reinterpret_cast<const float4*>(src) + (size_t)i * 2;
  float4 a = s[0], b = s[1];
  union { unsigned short h[8]; uint4 v; } p;
  p.h[0]=f2bf(a.x); p.h[1]=f2bf(a.y); p.h[2]=f2bf(a.z); p.h[3]=f2bf(a.w);
  p.h[4]=f2bf(b.x); p.h[5]=f2bf(b.y); p.h[6]=f2bf(b.z); p.h[7]=f2bf(b.w);
  reinterpret_cast<uint4*>(dst)[i] = p.v;
}

// ---------- transpose+convert: src[R][C] -> dst[C][R] bf16, batched via z ----------
template<typename Tin>
__global__ __launch_bounds__(1024)
void transpose_conv(const Tin* __restrict__ src, int ldsrc, size_t sstride,
                    unsigned short* __restrict__ dst, int lddst, size_t dstride) {
  __shared__ unsigned short tile[32][33];
  const Tin* s = src + (size_t)blockIdx.z * sstride;
  unsigned short* d = dst + (size_t)blockIdx.z * dstride;
  int tx = threadIdx.x, ty = threadIdx.y;
  int r = blockIdx.y * 32 + ty, c = blockIdx.x * 32 + tx;
  tile[ty][tx] = to_bf_bits(s[(size_t)r * ldsrc + c]);
  __syncthreads();
  d[(size_t)(blockIdx.x * 32 + ty) * lddst + blockIdx.y * 32 + tx] = tile[tx][ty];
}

// ---------- m201-style phased NT GEMM: C[M,N] = A[M,K]*B[N,K]^T ----------
// BM=256, BK=64, 8 waves (2M x 4N). BN=256: per-wave 128x64, 4 phases x 16 MFMA.
// BN=128: per-wave 128x32, 4 phases x 8 MFMA (kk-split).
// Half-tile staging slots chosen so the end-of-tile wait is counted
// (vmcnt(4)/vmcnt(2)), never 0 mid-loop. 7 barriers/tile.
#define EPI_QKV 0
#define EPI_F32 1
#define EPI_BF16 2
#define EPI_BIAS_F32 3

template<int BN, int EPI>
__global__ __launch_bounds__(512, 2)
void gemm8(const unsigned short* __restrict__ A, int lda, size_t sA,
           const unsigned short* __restrict__ B, int ldb, size_t sB,
           void* __restrict__ C, int ldc, size_t sC,
           const float* __restrict__ bias, int K) {
  constexpr int NREP = BN / 64;     // 4 or 2
  constexpr int NW = 16 * NREP;     // 64 or 32
  __shared__ unsigned short As[2 * 256 * 64];
  __shared__ unsigned short Bs[2 * BN * 64];

  const int tid = threadIdx.x;
  const int lane = tid & 63, wave = tid >> 6;
  const int wm = wave >> 2, wn = wave & 3;
  const int fr = lane & 15, fk = lane >> 4;
  const int tileM = blockIdx.y * 256, tileN = blockIdx.x * BN;
  const unsigned short* Ab = A + (size_t)blockIdx.z * sA;
  const unsigned short* Bb = B + (size_t)blockIdx.z * sB;

  // staging: one half = 128 rows of 128B = 2 rounds x (512 thr x 16B); linear LDS dest
  const int srow = tid >> 3;
  const int sg = (tid & 7) ^ (srow & 7);     // pre-swizzled source 16B-chunk

  auto stageA = [&](int buf, int half, int k0) {
#pragma unroll
    for (int q = 0; q < 2; ++q) {
      int rl = half * 128 + q * 64 + srow;
      gload_lds16(Ab + (size_t)(tileM + rl) * lda + k0 + sg * 8,
                  &As[buf * (256 * 64) + rl * 64 + (tid & 7) * 8]);
    }
  };
  auto stageB = [&](int buf, int half, int k0) {
#pragma unroll
    for (int q = 0; q < 2; ++q) {
      int rl = half * 128 + q * 64 + srow;
      gload_lds16(Bb + (size_t)(tileN + rl) * ldb + k0 + sg * 8,
                  &Bs[buf * (BN * 64) + rl * 64 + (tid & 7) * 8]);
    }
  };

  f32x4 acc[8][NREP];
#pragma unroll
  for (int m = 0; m < 8; ++m)
#pragma unroll
    for (int n = 0; n < NREP; ++n) acc[m][n] = (f32x4){0.f, 0.f, 0.f, 0.f};

  const int NS = K >> 6;
  const unsigned asb = (unsigned)(size_t)(__attribute__((address_space(3))) unsigned short*)As;
  const unsigned bsb = (unsigned)(size_t)(__attribute__((address_space(3))) unsigned short*)Bs;
  const unsigned aoff = (unsigned)((wm * 128 + fr) * 128 + ((fk ^ (fr & 7)) << 4));
  const unsigned boff = (unsigned)((wn * NW + fr) * 128 + ((fk ^ (fr & 7)) << 4));

  // prologue: B(0), A(0), B(1) — issue order defines vmcnt retire order
  if constexpr (BN == 256) {
    stageB(0, 0, 0); stageB(0, 1, 0); stageA(0, 0, 0); stageA(0, 1, 0);
    if (NS > 1) { stageB(1, 0, 64); stageB(1, 1, 64); WAITV(4); } else { WAITV(0); }
  } else {
    stageB(0, 0, 0); stageA(0, 0, 0); stageA(0, 1, 0);
    if (NS > 1) { stageB(1, 0, 64); WAITV(2); } else { WAITV(0); }
  }
  BAR();

  bf16x8 afLo[4][2], afHi[4][2], bgA[2][2], bgB[2][2];

  for (int t = 0; t < NS; ++t) {
    const int cb = t & 1, nb = cb ^ 1;
    const unsigned aA0 = asb + (unsigned)cb * 32768u + aoff, aA1 = aA0 ^ 64u;
    const unsigned bB0 = bsb + (unsigned)cb * (unsigned)(BN * 128) + boff, bB1 = bB0 ^ 64u;
    const int k1 = (t + 1) << 6, k2 = (t + 2) << 6;

    if constexpr (BN == 256) {
      // ---- ph0: read Alo(8)+Blo(4) | stage hA0(t+1) | MFMA m0-3 x n0-1 ----
      DSR(afLo[0][0], aA0, 0); DSR(afLo[1][0], aA0, 2048); DSR(afLo[2][0], aA0, 4096); DSR(afLo[3][0], aA0, 6144);
      DSR(afLo[0][1], aA1, 0); DSR(afLo[1][1], aA1, 2048); DSR(afLo[2][1], aA1, 4096); DSR(afLo[3][1], aA1, 6144);
      DSR(bgA[0][0], bB0, 0); DSR(bgA[1][0], bB0, 2048);
      DSR(bgA[0][1], bB1, 0); DSR(bgA[1][1], bB1, 2048);
      if (t + 1 < NS) stageA(nb, 0, k1);
      BAR(); WAITL0(); SCHED0();
      PRIO(1);
#pragma unroll
      for (int kk = 0; kk < 2; ++kk)
#pragma unroll
        for (int m = 0; m < 4; ++m)
#pragma unroll
          for (int n = 0; n < 2; ++n)
            acc[m][n] = __builtin_amdgcn_mfma_f32_16x16x32_bf16(afLo[m][kk], bgA[n][kk], acc[m][n], 0, 0, 0);
      PRIO(0); SCHED0();
      BAR();
      // ---- ph1: read Bhi(4) | stage hA1(t+1), hB0(t+2) | MFMA m0-3 x n2-3 ----
      DSR(bgB[0][0], bB0, 4096); DSR(bgB[1][0], bB0, 6144);
      DSR(bgB[0][1], bB1, 4096); DSR(bgB[1][1], bB1, 6144);
      if (t + 1 < NS) stageA(nb, 1, k1);
      if (t + 2 < NS) stageB(cb, 0, k2);
      BAR(); WAITL0(); SCHED0();
      PRIO(1);
#pragma unroll
      for (int kk = 0; kk < 2; ++kk)
#pragma unroll
        for (int m = 0; m < 4; ++m)
#pragma unroll
          for (int n = 0; n < 2; ++n)
            acc[m][2 + n] = __builtin_amdgcn_mfma_f32_16x16x32_bf16(afLo[m][kk], bgB[n][kk], acc[m][2 + n], 0, 0, 0);
      PRIO(0); SCHED0();
      BAR();
      // ---- ph2: read Ahi(8) | stage hB1(t+2) | MFMA m4-7 x n0-1 ----
      DSR(afHi[0][0], aA0, 8192); DSR(afHi[1][0], aA0, 10240); DSR(afHi[2][0], aA0, 12288); DSR(afHi[3][0], aA0, 14336);
      DSR(afHi[0][1], aA1, 8192); DSR(afHi[1][1], aA1, 10240); DSR(afHi[2][1], aA1, 12288); DSR(afHi[3][1], aA1, 14336);
      if (t + 2 < NS) stageB(cb, 1, k2);
      BAR(); WAITL0(); SCHED0();
      PRIO(1);
#pragma unroll
      for (int kk = 0; kk < 2; ++kk)
#pragma unroll
        for (int m = 0; m < 4; ++m)
#pragma unroll
          for (int n = 0; n < 2; ++n)
            acc[4 + m][n] = __builtin_amdgcn_mfma_f32_16x16x32_bf16(afHi[m][kk], bgA[n][kk], acc[4 + m][n], 0, 0, 0);
      PRIO(0); SCHED0();
      BAR();
      // ---- ph3: MFMA m4-7 x n2-3 | counted vmcnt | tile boundary ----
      PRIO(1);
#pragma unroll
      for (int kk = 0; kk < 2; ++kk)
#pragma unroll
        for (int m = 0; m < 4; ++m)
#pragma unroll
          for (int n = 0; n < 2; ++n)
            acc[4 + m][2 + n] = __builtin_amdgcn_mfma_f32_16x16x32_bf16(afHi[m][kk], bgB[n][kk], acc[4 + m][2 + n], 0, 0, 0);
      PRIO(0); SCHED0();
      if (t + 1 < NS) { if (t + 2 < NS) { WAITV(4); } else { WAITV(0); } }
      BAR();
    } else {
      // ---- ph0: read Alo-kk0(4)+B-kk0(2) | stage hA0(t+1) | MFMA m0-3 kk0 ----
      DSR(afLo[0][0], aA0, 0); DSR(afLo[1][0], aA0, 2048); DSR(afLo[2][0], aA0, 4096); DSR(afLo[3][0], aA0, 6144);
      DSR(bgA[0][0], bB0, 0); DSR(bgA[1][0], bB0, 2048);
      if (t + 1 < NS) stageA(nb, 0, k1);
      BAR(); WAITL0(); SCHED0();
      PRIO(1);
#pragma unroll
      for (int m = 0; m < 4; ++m)
#pragma unroll
        for (int n = 0; n < 2; ++n)
          acc[m][n] = __builtin_amdgcn_mfma_f32_16x16x32_bf16(afLo[m][0], bgA[n][0], acc[m][n], 0, 0, 0);
      PRIO(0); SCHED0();
      BAR();
      // ---- ph1: read Alo-kk1(4)+B-kk1(2) | stage hA1(t+1) | MFMA m0-3 kk1 ----
      DSR(afLo[0][1], aA1, 0); DSR(afLo[1][1], aA1, 2048); DSR(afLo[2][1], aA1, 4096); DSR(afLo[3][1], aA1, 6144);
      DSR(bgA[0][1], bB1, 0); DSR(bgA[1][1], bB1, 2048);
      if (t + 1 < NS) stageA(nb, 1, k1);
      BAR(); WAITL0(); SCHED0();
      PRIO(1);
#pragma unroll
      for (int m = 0; m < 4; ++m)
#pragma unroll
        for (int n = 0; n < 2; ++n)
          acc[m][n] = __builtin_amdgcn_mfma_f32_16x16x32_bf16(afLo[m][1], bgA[n][1], acc[m][n], 0, 0, 0);
      PRIO(0); SCHED0();
      BAR();
      // ---- ph2: read Ahi kk0+kk1 (8) | stage hB(t+2) | MFMA m4-7 kk0 ----
      DSR(afHi[0][0], aA0, 8192); DSR(afHi[1][0], aA0, 10240); DSR(afHi[2][0], aA0, 12288); DSR(afHi[3][0], aA0, 14336);
      DSR(afHi[0][1], aA1, 8192); DSR(afHi[1][1], aA1, 10240); DSR(afHi[2][1], aA1, 12288); DSR(afHi[3][1], aA1, 14336);
      if (t + 2 < NS) stageB(cb, 0, k2);
      BAR(); WAITL0(); SCHED0();
      PRIO(1);
#pragma unroll
      for (int m = 0; m < 4; ++m)
#pragma unroll
        for (int n = 0; n < 2; ++n)
          acc[4 + m][n] = __builtin_amdgcn_mfma_f32_16x16x32_bf16(afHi[m][0], bgA[n][0], acc[4 + m][n], 0, 0, 0);
      PRIO(0); SCHED0();
      BAR();
      // ---- ph3: MFMA m4-7 kk1 | counted vmcnt | tile boundary ----
      PRIO(1);
#pragma unroll
      for (int m = 0; m < 4; ++m)
#pragma unroll
        for (int n = 0; n < 2; ++n)
          acc[4 + m][n] = __builtin_amdgcn_mfma_f32_16x16x32_bf16(afHi[m][1], bgA[n][1], acc[4 + m][n], 0, 0, 0);
      PRIO(0); SCHED0();
      if (t + 1 < NS) { if (t + 2 < NS) { WAITV(2); } else { WAITV(0); } }
      BAR();
    }
  }

#pragma unroll
  for (int m = 0; m < 8; ++m)
#pragma unroll
    for (int n = 0; n < NREP; ++n)
#pragma unroll
      for (int j = 0; j < 4; ++j) {
        int row = tileM + wm * 128 + m * 16 + fk * 4 + j;
        int col = tileN + wn * NW + n * 16 + fr;
        float v = acc[m][n][j];
        if (EPI == EPI_QKV) {
          v += bias[col];
          if (col < DIM) v *= 0.03125f;   // 1/sqrt(1024)
          ((unsigned short*)C + (size_t)blockIdx.z * sC)[(size_t)row * ldc + col] = f2bf(v);
        } else if (EPI == EPI_BF16) {
          ((unsigned short*)C + (size_t)blockIdx.z * sC)[(size_t)row * ldc + col] = f2bf(v);
        } else if (EPI == EPI_BIAS_F32) {
          ((float*)C + (size_t)blockIdx.z * sC)[(size_t)row * ldc + col] = v + bias[col];
        } else {
          ((float*)C + (size_t)blockIdx.z * sC)[(size_t)row * ldc + col] = v;
        }
      }
}

// ---------- row softmax, in-place: fp32 row -> bf16 P at row start ----------
__global__ __launch_bounds__(256)
void softmax_kernel(float* __restrict__ S, size_t zstride) {
  __shared__ float red[8];
  float* row = S + (size_t)blockIdx.y * zstride + (size_t)blockIdx.x * SEQ;
  const int tid = threadIdx.x;
  const int lane = tid & 63, wave = tid >> 6;
  const float4* src = reinterpret_cast<const float4*>(row) + tid * 2;
  float4 a = src[0], b = src[1];
  float v[8] = {a.x, a.y, a.z, a.w, b.x, b.y, b.z, b.w};
  float m = v[0];
#pragma unroll
  for (int i = 1; i < 8; ++i) m = fmaxf(m, v[i]);
  for (int o = 32; o; o >>= 1) m = fmaxf(m, __shfl_xor(m, o));
  if (lane == 0) red[wave] = m;
  __syncthreads();
  m = fmaxf(fmaxf(red[0], red[1]), fmaxf(red[2], red[3]));
  float e[8], s = 0.f;
#pragma unroll
  for (int i = 0; i < 8; ++i) { e[i] = expf(v[i] - m); s += e[i]; }
  for (int o = 32; o; o >>= 1) s += __shfl_xor(s, o);
  if (lane == 0) red[4 + wave] = s;
  __syncthreads();
  s = red[4] + red[5] + red[6] + red[7];
  float inv = 1.f / s;
  union { unsigned short h[8]; uint4 u; } p;
#pragma unroll
  for (int i = 0; i < 8; ++i) p.h[i] = f2bf(e[i] * inv);
  reinterpret_cast<uint4*>(row)[tid] = p.u;
}

extern "C" void kernel_launch(void* const* d_in, const int* in_sizes, int n_in,
                              void* d_out, int out_size, void* d_ws, size_t ws_size,
                              hipStream_t stream) {
  const float* X     = (const float*)d_in[0];
  const float* W_in  = (const float*)d_in[1];
  const float* b_in  = (const float*)d_in[2];
  const float* W_out = (const float*)d_in[3];
  const float* b_out = (const float*)d_in[4];
  float* out = (float*)d_out;
  char* ws = (char*)d_ws;

  size_t o = 0;
  auto alloc = [&](size_t bytes) { size_t r = o; o += (bytes + 255) & ~(size_t)255; return r; };
  unsigned short* Xbf   = (unsigned short*)(ws + alloc((size_t)ROWS * DIM * 2));     // aliased as O later
  unsigned short* WinT  = (unsigned short*)(ws + alloc((size_t)3 * DIM * DIM * 2));
  unsigned short* WoutT = (unsigned short*)(ws + alloc((size_t)DIM * DIM * 2));
  unsigned short* QKV   = (unsigned short*)(ws + alloc((size_t)ROWS * 3 * DIM * 2));
  size_t fixed = o;
  size_t per_batch = (((size_t)SEQ * SEQ * 4 + 255) & ~(size_t)255) +
                     (((size_t)DIM * SEQ * 2 + 255) & ~(size_t)255);
  int G = (ws_size >= fixed + 4 * per_batch) ? BATCH : 1;
  float*          Sc = (float*)(ws + alloc((size_t)G * SEQ * SEQ * 4));  // P written in place (bf16)
  unsigned short* Vt = (unsigned short*)(ws + alloc((size_t)G * DIM * SEQ * 2));
  unsigned short* O  = Xbf;   // Xbf dead after QKV GEMM

  conv_f32_bf16<<<(ROWS * DIM / 8 + 255) / 256, 256, 0, stream>>>(X, Xbf, ROWS * DIM / 8);
  transpose_conv<float><<<dim3(3 * DIM / 32, DIM / 32, 1), dim3(32, 32), 0, stream>>>(
      W_in, 3 * DIM, 0, WinT, DIM, 0);
  transpose_conv<float><<<dim3(DIM / 32, DIM / 32, 1), dim3(32, 32), 0, stream>>>(
      W_out, DIM, 0, WoutT, DIM, 0);
  gemm8<256, EPI_QKV><<<dim3(3 * DIM / 256, ROWS / 256, 1), 512, 0, stream>>>(
      Xbf, DIM, 0, WinT, DIM, 0, QKV, 3 * DIM, 0, b_in, DIM);

  for (int b0 = 0; b0 < BATCH; b0 += G) {
    const unsigned short* Qb = QKV + (size_t)b0 * SEQ * 3 * DIM;
    const unsigned short* Kb = Qb + DIM;
    const unsigned short* Vb = Qb + 2 * DIM;
    transpose_conv<unsigned short><<<dim3(DIM / 32, SEQ / 32, G), dim3(32, 32), 0, stream>>>(
        Vb, 3 * DIM, (size_t)SEQ * 3 * DIM, Vt, SEQ, (size_t)DIM * SEQ);
    gemm8<256, EPI_F32><<<dim3(SEQ / 256, SEQ / 256, G), 512, 0, stream>>>(
        Qb, 3 * DIM, (size_t)SEQ * 3 * DIM, Kb, 3 * DIM, (size_t)SEQ * 3 * DIM,
        Sc, SEQ, (size_t)SEQ * SEQ, nullptr, DIM);
    softmax_kernel<<<dim3(SEQ, G), 256, 0, stream>>>(Sc, (size_t)SEQ * SEQ);
    gemm8<128, EPI_BF16><<<dim3(DIM / 128, SEQ / 256, G), 512, 0, stream>>>(
        (const unsigned short*)Sc, 2 * SEQ, (size_t)2 * SEQ * SEQ,
        Vt, SEQ, (size_t)DIM * SEQ,
        O + (size_t)b0 * SEQ * DIM, DIM, (size_t)SEQ * DIM, nullptr, SEQ);
  }
  gemm8<128, EPI_BIAS_F32><<<dim3(DIM / 128, ROWS / 256, 1), 512, 0, stream>>>(
      O, DIM, 0, WoutT, DIM, 0, out, DIM, 0, b_out, DIM);
}

// Round 6
// 228.527 us; speedup vs baseline: 1.0699x; 1.0043x over previous
//
#include <hip/hip_runtime.h>
#include <hip/hip_bf16.h>
#include <math.h>

typedef __attribute__((ext_vector_type(8))) __bf16 bf16x8;
typedef __attribute__((ext_vector_type(4))) float f32x4;
typedef __attribute__((ext_vector_type(4))) unsigned int u32x4;

#define DIM 1024
#define SEQ 2048
#define BATCH 4
#define ROWS (BATCH*SEQ)

#define BAR() do { asm volatile("" ::: "memory"); __builtin_amdgcn_s_barrier(); asm volatile("" ::: "memory"); } while(0)
#define WAITV(n) asm volatile("s_waitcnt vmcnt(" #n ")" ::: "memory")
#define WAITL(n) asm volatile("s_waitcnt lgkmcnt(" #n ")" ::: "memory")
#define SCHED0() __builtin_amdgcn_sched_barrier(0)
#define PRIO(x) __builtin_amdgcn_s_setprio(x)

// inline-asm LDS read: escapes auto-waitcnt; ordered manually via WAITL/WAITV.
#define DSR(d, a, off) do { u32x4 _t; \
  asm volatile("ds_read_b128 %0, %1 offset:" #off : "=v"(_t) : "v"(a)); \
  (d) = __builtin_bit_cast(bf16x8, _t); } while(0)

__device__ __forceinline__ unsigned short f2bf(float f) {
  unsigned int u = __float_as_uint(f);
  u += 0x7FFF + ((u >> 16) & 1);   // RNE
  return (unsigned short)(u >> 16);
}
__device__ __forceinline__ unsigned short to_bf_bits(float v) { return f2bf(v); }
__device__ __forceinline__ unsigned short to_bf_bits(unsigned short v) { return v; }

__device__ __forceinline__ void gload_lds16(const void* g, void* lds) {
  __builtin_amdgcn_global_load_lds((__attribute__((address_space(1))) void*)g,
                                   (__attribute__((address_space(3))) void*)lds,
                                   16, 0, 0);
}

// ---------- f32 -> bf16 ----------
__global__ __launch_bounds__(256)
void conv_f32_bf16(const float* __restrict__ src, unsigned short* __restrict__ dst, int n8) {
  int i = blockIdx.x * blockDim.x + threadIdx.x;
  if (i >= n8) return;
  const float4* s = reinterpret_cast<const float4*>(src) + (size_t)i * 2;
  float4 a = s[0], b = s[1];
  union { unsigned short h[8]; uint4 v; } p;
  p.h[0]=f2bf(a.x); p.h[1]=f2bf(a.y); p.h[2]=f2bf(a.z); p.h[3]=f2bf(a.w);
  p.h[4]=f2bf(b.x); p.h[5]=f2bf(b.y); p.h[6]=f2bf(b.z); p.h[7]=f2bf(b.w);
  reinterpret_cast<uint4*>(dst)[i] = p.v;
}

// ---------- transpose+convert: src[R][C] -> dst[C][R] bf16, batched via z ----------
template<typename Tin>
__global__ __launch_bounds__(1024)
void transpose_conv(const Tin* __restrict__ src, int ldsrc, size_t sstride,
                    unsigned short* __restrict__ dst, int lddst, size_t dstride) {
  __shared__ unsigned short tile[32][33];
  const Tin* s = src + (size_t)blockIdx.z * sstride;
  unsigned short* d = dst + (size_t)blockIdx.z * dstride;
  int tx = threadIdx.x, ty = threadIdx.y;
  int r = blockIdx.y * 32 + ty, c = blockIdx.x * 32 + tx;
  tile[ty][tx] = to_bf_bits(s[(size_t)r * ldsrc + c]);
  __syncthreads();
  d[(size_t)(blockIdx.x * 32 + ty) * lddst + blockIdx.y * 32 + tx] = tile[tx][ty];
}

// ---------- phase-overlapped NT GEMM: C[M,N] = A[M,K]*B[N,K]^T ----------
// BM=256, BK=64, 8 waves (2M x 4N). One-phase-ahead register prefetch:
// each phase issues the NEXT phase's ds_reads, then waits only older reads
// (counted lgkmcnt) so its MFMA cluster overlaps the younger reads.
// vmcnt counted (4/2), drained only at tail. WAITV always precedes a barrier
// before any cross-wave read of staged data.
#define EPI_QKV 0
#define EPI_F32 1
#define EPI_BF16 2
#define EPI_BIAS_F32 3

template<int BN, int EPI>
__global__ __launch_bounds__(512, 2)
void gemm8(const unsigned short* __restrict__ A, int lda, size_t sA,
           const unsigned short* __restrict__ B, int ldb, size_t sB,
           void* __restrict__ C, int ldc, size_t sC,
           const float* __restrict__ bias, int K) {
  constexpr int NREP = BN / 64;     // 4 or 2
  constexpr int NW = 16 * NREP;     // 64 or 32
  __shared__ unsigned short As[2 * 256 * 64];
  __shared__ unsigned short Bs[2 * BN * 64];

  const int tid = threadIdx.x;
  const int lane = tid & 63, wave = tid >> 6;
  const int wm = wave >> 2, wn = wave & 3;
  const int fr = lane & 15, fk = lane >> 4;
  const int tileM = blockIdx.y * 256, tileN = blockIdx.x * BN;
  const unsigned short* Ab = A + (size_t)blockIdx.z * sA;
  const unsigned short* Bb = B + (size_t)blockIdx.z * sB;

  const int srow = tid >> 3;
  const int sg = (tid & 7) ^ (srow & 7);     // pre-swizzled source 16B-chunk

  auto stageA = [&](int buf, int half, int k0) {
#pragma unroll
    for (int q = 0; q < 2; ++q) {
      int rl = half * 128 + q * 64 + srow;
      gload_lds16(Ab + (size_t)(tileM + rl) * lda + k0 + sg * 8,
                  &As[buf * (256 * 64) + rl * 64 + (tid & 7) * 8]);
    }
  };
  auto stageB = [&](int buf, int half, int k0) {
#pragma unroll
    for (int q = 0; q < 2; ++q) {
      int rl = half * 128 + q * 64 + srow;
      gload_lds16(Bb + (size_t)(tileN + rl) * ldb + k0 + sg * 8,
                  &Bs[buf * (BN * 64) + rl * 64 + (tid & 7) * 8]);
    }
  };

  f32x4 acc[8][NREP];
#pragma unroll
  for (int m = 0; m < 8; ++m)
#pragma unroll
    for (int n = 0; n < NREP; ++n) acc[m][n] = (f32x4){0.f, 0.f, 0.f, 0.f};

  const int NS = K >> 6;
  const unsigned asb = (unsigned)(size_t)(__attribute__((address_space(3))) unsigned short*)As;
  const unsigned bsb = (unsigned)(size_t)(__attribute__((address_space(3))) unsigned short*)Bs;
  const unsigned aoff = (unsigned)((wm * 128 + fr) * 128 + ((fk ^ (fr & 7)) << 4));
  const unsigned boff = (unsigned)((wn * NW + fr) * 128 + ((fk ^ (fr & 7)) << 4));
  auto aBase = [&](int b) { return asb + (unsigned)b * 32768u + aoff; };
  auto bBase = [&](int b) { return bsb + (unsigned)b * (unsigned)(BN * 128) + boff; };

  if constexpr (BN == 256) {
    bf16x8 afLo[4][2], afHi[4][2], bgA[2][2], bgB[2][2];
    // prologue: B(0), A(0), B(1); fence; pre-read afLo(0)+bgA(0)
    stageB(0, 0, 0); stageB(0, 1, 0); stageA(0, 0, 0); stageA(0, 1, 0);
    if (NS > 1) { stageB(1, 0, 64); stageB(1, 1, 64); WAITV(4); } else { WAITV(0); }
    BAR();
    {
      unsigned a0 = aBase(0), a1 = a0 ^ 64u, b0 = bBase(0), b1 = b0 ^ 64u;
      DSR(afLo[0][0], a0, 0); DSR(afLo[1][0], a0, 2048); DSR(afLo[2][0], a0, 4096); DSR(afLo[3][0], a0, 6144);
      DSR(afLo[0][1], a1, 0); DSR(afLo[1][1], a1, 2048); DSR(afLo[2][1], a1, 4096); DSR(afLo[3][1], a1, 6144);
      DSR(bgA[0][0], b0, 0); DSR(bgA[1][0], b0, 2048);
      DSR(bgA[0][1], b1, 0); DSR(bgA[1][1], b1, 2048);
    }
    for (int t = 0; t < NS; ++t) {
      const int cb = t & 1, nb = cb ^ 1;
      const unsigned cA0 = aBase(cb), cA1 = cA0 ^ 64u, cB0 = bBase(cb), cB1 = cB0 ^ 64u;
      const unsigned nA0 = aBase(nb), nA1 = nA0 ^ 64u, nB0 = bBase(nb), nB1 = nB0 ^ 64u;
      const int k1 = (t + 1) << 6, k2 = (t + 2) << 6;
      // ph0: issue bgB | stage hA0(t+1) | MFMA S0 (afLo x bgA)
      DSR(bgB[0][0], cB0, 4096); DSR(bgB[1][0], cB0, 6144);
      DSR(bgB[0][1], cB1, 4096); DSR(bgB[1][1], cB1, 6144);
      if (t + 1 < NS) stageA(nb, 0, k1);
      BAR(); WAITL(4); SCHED0();
      PRIO(1);
#pragma unroll
      for (int kk = 0; kk < 2; ++kk)
#pragma unroll
        for (int m = 0; m < 4; ++m)
#pragma unroll
          for (int n = 0; n < 2; ++n)
            acc[m][n] = __builtin_amdgcn_mfma_f32_16x16x32_bf16(afLo[m][kk], bgA[n][kk], acc[m][n], 0, 0, 0);
      PRIO(0); SCHED0();
      BAR();
      // ph1: issue afHi | stage hA1(t+1), hB0(t+2) | MFMA S1 (afLo x bgB)
      DSR(afHi[0][0], cA0, 8192); DSR(afHi[1][0], cA0, 10240); DSR(afHi[2][0], cA0, 12288); DSR(afHi[3][0], cA0, 14336);
      DSR(afHi[0][1], cA1, 8192); DSR(afHi[1][1], cA1, 10240); DSR(afHi[2][1], cA1, 12288); DSR(afHi[3][1], cA1, 14336);
      if (t + 1 < NS) stageA(nb, 1, k1);
      if (t + 2 < NS) stageB(cb, 0, k2);
      BAR(); WAITL(8); SCHED0();
      PRIO(1);
#pragma unroll
      for (int kk = 0; kk < 2; ++kk)
#pragma unroll
        for (int m = 0; m < 4; ++m)
#pragma unroll
          for (int n = 0; n < 2; ++n)
            acc[m][2 + n] = __builtin_amdgcn_mfma_f32_16x16x32_bf16(afLo[m][kk], bgB[n][kk], acc[m][2 + n], 0, 0, 0);
      PRIO(0); SCHED0();
      BAR();
      // ph2: stage hB1(t+2) | MFMA S2 (afHi x bgA) | counted vmcnt + fence
      if (t + 2 < NS) stageB(cb, 1, k2);
      BAR(); WAITL(0); SCHED0();
      PRIO(1);
#pragma unroll
      for (int kk = 0; kk < 2; ++kk)
#pragma unroll
        for (int m = 0; m < 4; ++m)
#pragma unroll
          for (int n = 0; n < 2; ++n)
            acc[4 + m][n] = __builtin_amdgcn_mfma_f32_16x16x32_bf16(afHi[m][kk], bgA[n][kk], acc[4 + m][n], 0, 0, 0);
      PRIO(0); SCHED0();
      if (t + 1 < NS) { if (t + 2 < NS) { WAITV(4); } else { WAITV(0); } }
      BAR();
      // ph3: issue afLo'(t+1)+bgA'(t+1) | MFMA S3 (afHi x bgB) — overlap
      if (t + 1 < NS) {
        DSR(afLo[0][0], nA0, 0); DSR(afLo[1][0], nA0, 2048); DSR(afLo[2][0], nA0, 4096); DSR(afLo[3][0], nA0, 6144);
        DSR(afLo[0][1], nA1, 0); DSR(afLo[1][1], nA1, 2048); DSR(afLo[2][1], nA1, 4096); DSR(afLo[3][1], nA1, 6144);
        DSR(bgA[0][0], nB0, 0); DSR(bgA[1][0], nB0, 2048);
        DSR(bgA[0][1], nB1, 0); DSR(bgA[1][1], nB1, 2048);
      }
      SCHED0();
      PRIO(1);
#pragma unroll
      for (int kk = 0; kk < 2; ++kk)
#pragma unroll
        for (int m = 0; m < 4; ++m)
#pragma unroll
          for (int n = 0; n < 2; ++n)
            acc[4 + m][2 + n] = __builtin_amdgcn_mfma_f32_16x16x32_bf16(afHi[m][kk], bgB[n][kk], acc[4 + m][2 + n], 0, 0, 0);
      PRIO(0); SCHED0();
      BAR();
    }
  } else {
    bf16x8 a0f[4], a1f[4], h0f[4], h1f[4], b0f[2], b1f[2];
    // prologue: B(0), A(0), B(1); fence; pre-read a0f(0)+b0f(0)
    stageB(0, 0, 0); stageA(0, 0, 0); stageA(0, 1, 0);
    if (NS > 1) { stageB(1, 0, 64); WAITV(2); } else { WAITV(0); }
    BAR();
    {
      unsigned a0 = aBase(0), b0 = bBase(0);
      DSR(a0f[0], a0, 0); DSR(a0f[1], a0, 2048); DSR(a0f[2], a0, 4096); DSR(a0f[3], a0, 6144);
      DSR(b0f[0], b0, 0); DSR(b0f[1], b0, 2048);
    }
    for (int t = 0; t < NS; ++t) {
      const int cb = t & 1, nb = cb ^ 1;
      const unsigned cA0 = aBase(cb), cA1 = cA0 ^ 64u, cB0 = bBase(cb), cB1 = cB0 ^ 64u;
      const unsigned nA0 = aBase(nb), nB0 = bBase(nb);
      const int k1 = (t + 1) << 6, k2 = (t + 2) << 6;
      // ph0: issue a1f,b1f | stage hA0(t+1) | MFMA S0 (a0f x b0f, kk0)
      DSR(a1f[0], cA1, 0); DSR(a1f[1], cA1, 2048); DSR(a1f[2], cA1, 4096); DSR(a1f[3], cA1, 6144);
      DSR(b1f[0], cB1, 0); DSR(b1f[1], cB1, 2048);
      if (t + 1 < NS) stageA(nb, 0, k1);
      BAR(); WAITL(6); SCHED0();
      PRIO(1);
#pragma unroll
      for (int m = 0; m < 4; ++m)
#pragma unroll
        for (int n = 0; n < 2; ++n)
          acc[m][n] = __builtin_amdgcn_mfma_f32_16x16x32_bf16(a0f[m], b0f[n], acc[m][n], 0, 0, 0);
      PRIO(0); SCHED0();
      BAR();
      // ph1: issue h0f | stage hA1(t+1) | MFMA S1 (a1f x b1f, kk1)
      DSR(h0f[0], cA0, 8192); DSR(h0f[1], cA0, 10240); DSR(h0f[2], cA0, 12288); DSR(h0f[3], cA0, 14336);
      if (t + 1 < NS) stageA(nb, 1, k1);
      BAR(); WAITL(4); SCHED0();
      PRIO(1);
#pragma unroll
      for (int m = 0; m < 4; ++m)
#pragma unroll
        for (int n = 0; n < 2; ++n)
          acc[m][n] = __builtin_amdgcn_mfma_f32_16x16x32_bf16(a1f[m], b1f[n], acc[m][n], 0, 0, 0);
      PRIO(0); SCHED0();
      BAR();
      // ph2: issue h1f | stage hB0(t+2) | MFMA S2 (h0f x b0f) | vmcnt fence
      DSR(h1f[0], cA1, 8192); DSR(h1f[1], cA1, 10240); DSR(h1f[2], cA1, 12288); DSR(h1f[3], cA1, 14336);
      if (t + 2 < NS) stageB(cb, 0, k2);
      BAR(); WAITL(4); SCHED0();
      PRIO(1);
#pragma unroll
      for (int m = 0; m < 4; ++m)
#pragma unroll
        for (int n = 0; n < 2; ++n)
          acc[4 + m][n] = __builtin_amdgcn_mfma_f32_16x16x32_bf16(h0f[m], b0f[n], acc[4 + m][n], 0, 0, 0);
      PRIO(0); SCHED0();
      if (t + 1 < NS) { if (t + 2 < NS) { WAITV(2); } else { WAITV(0); } }
      BAR();
      // ph3: issue a0f',b0f'(t+1) | wait h1f only | MFMA S3 (h1f x b1f)
      if (t + 1 < NS) {
        DSR(a0f[0], nA0, 0); DSR(a0f[1], nA0, 2048); DSR(a0f[2], nA0, 4096); DSR(a0f[3], nA0, 6144);
        DSR(b0f[0], nB0, 0); DSR(b0f[1], nB0, 2048);
        WAITL(6);
      } else {
        WAITL(0);
      }
      SCHED0();
      PRIO(1);
#pragma unroll
      for (int m = 0; m < 4; ++m)
#pragma unroll
        for (int n = 0; n < 2; ++n)
          acc[4 + m][n] = __builtin_amdgcn_mfma_f32_16x16x32_bf16(h1f[m], b1f[n], acc[4 + m][n], 0, 0, 0);
      PRIO(0); SCHED0();
      BAR();
    }
  }

#pragma unroll
  for (int m = 0; m < 8; ++m)
#pragma unroll
    for (int n = 0; n < NREP; ++n)
#pragma unroll
      for (int j = 0; j < 4; ++j) {
        int row = tileM + wm * 128 + m * 16 + fk * 4 + j;
        int col = tileN + wn * NW + n * 16 + fr;
        float v = acc[m][n][j];
        if (EPI == EPI_QKV) {
          v += bias[col];
          if (col < DIM) v *= 0.03125f;   // 1/sqrt(1024)
          ((unsigned short*)C + (size_t)blockIdx.z * sC)[(size_t)row * ldc + col] = f2bf(v);
        } else if (EPI == EPI_BF16) {
          ((unsigned short*)C + (size_t)blockIdx.z * sC)[(size_t)row * ldc + col] = f2bf(v);
        } else if (EPI == EPI_BIAS_F32) {
          ((float*)C + (size_t)blockIdx.z * sC)[(size_t)row * ldc + col] = v + bias[col];
        } else {
          ((float*)C + (size_t)blockIdx.z * sC)[(size_t)row * ldc + col] = v;
        }
      }
}

// ---------- row softmax, in-place: fp32 row -> bf16 P at row start ----------
__global__ __launch_bounds__(256)
void softmax_kernel(float* __restrict__ S, size_t zstride) {
  __shared__ float red[8];
  float* row = S + (size_t)blockIdx.y * zstride + (size_t)blockIdx.x * SEQ;
  const int tid = threadIdx.x;
  const int lane = tid & 63, wave = tid >> 6;
  const float4* src = reinterpret_cast<const float4*>(row) + tid * 2;
  float4 a = src[0], b = src[1];
  float v[8] = {a.x, a.y, a.z, a.w, b.x, b.y, b.z, b.w};
  float m = v[0];
#pragma unroll
  for (int i = 1; i < 8; ++i) m = fmaxf(m, v[i]);
  for (int o = 32; o; o >>= 1) m = fmaxf(m, __shfl_xor(m, o));
  if (lane == 0) red[wave] = m;
  __syncthreads();
  m = fmaxf(fmaxf(red[0], red[1]), fmaxf(red[2], red[3]));
  float e[8], s = 0.f;
#pragma unroll
  for (int i = 0; i < 8; ++i) { e[i] = expf(v[i] - m); s += e[i]; }
  for (int o = 32; o; o >>= 1) s += __shfl_xor(s, o);
  if (lane == 0) red[4 + wave] = s;
  __syncthreads();
  s = red[4] + red[5] + red[6] + red[7];
  float inv = 1.f / s;
  union { unsigned short h[8]; uint4 u; } p;
#pragma unroll
  for (int i = 0; i < 8; ++i) p.h[i] = f2bf(e[i] * inv);
  reinterpret_cast<uint4*>(row)[tid] = p.u;
}

extern "C" void kernel_launch(void* const* d_in, const int* in_sizes, int n_in,
                              void* d_out, int out_size, void* d_ws, size_t ws_size,
                              hipStream_t stream) {
  const float* X     = (const float*)d_in[0];
  const float* W_in  = (const float*)d_in[1];
  const float* b_in  = (const float*)d_in[2];
  const float* W_out = (const float*)d_in[3];
  const float* b_out = (const float*)d_in[4];
  float* out = (float*)d_out;
  char* ws = (char*)d_ws;

  size_t o = 0;
  auto alloc = [&](size_t bytes) { size_t r = o; o += (bytes + 255) & ~(size_t)255; return r; };
  unsigned short* Xbf   = (unsigned short*)(ws + alloc((size_t)ROWS * DIM * 2));     // aliased as O later
  unsigned short* WinT  = (unsigned short*)(ws + alloc((size_t)3 * DIM * DIM * 2));
  unsigned short* WoutT = (unsigned short*)(ws + alloc((size_t)DIM * DIM * 2));
  unsigned short* QKV   = (unsigned short*)(ws + alloc((size_t)ROWS * 3 * DIM * 2));
  size_t fixed = o;
  size_t per_batch = (((size_t)SEQ * SEQ * 4 + 255) & ~(size_t)255) +
                     (((size_t)DIM * SEQ * 2 + 255) & ~(size_t)255);
  int G = (ws_size >= fixed + 4 * per_batch) ? BATCH : 1;
  float*          Sc = (float*)(ws + alloc((size_t)G * SEQ * SEQ * 4));  // P written in place (bf16)
  unsigned short* Vt = (unsigned short*)(ws + alloc((size_t)G * DIM * SEQ * 2));
  unsigned short* O  = Xbf;   // Xbf dead after QKV GEMM

  conv_f32_bf16<<<(ROWS * DIM / 8 + 255) / 256, 256, 0, stream>>>(X, Xbf, ROWS * DIM / 8);
  transpose_conv<float><<<dim3(3 * DIM / 32, DIM / 32, 1), dim3(32, 32), 0, stream>>>(
      W_in, 3 * DIM, 0, WinT, DIM, 0);
  transpose_conv<float><<<dim3(DIM / 32, DIM / 32, 1), dim3(32, 32), 0, stream>>>(
      W_out, DIM, 0, WoutT, DIM, 0);
  // QKV: BN=128 -> grid 24x32 = 768 = 3 full rounds of 256 CUs
  gemm8<128, EPI_QKV><<<dim3(3 * DIM / 128, ROWS / 256, 1), 512, 0, stream>>>(
      Xbf, DIM, 0, WinT, DIM, 0, QKV, 3 * DIM, 0, b_in, DIM);

  for (int b0 = 0; b0 < BATCH; b0 += G) {
    const unsigned short* Qb = QKV + (size_t)b0 * SEQ * 3 * DIM;
    const unsigned short* Kb = Qb + DIM;
    const unsigned short* Vb = Qb + 2 * DIM;
    transpose_conv<unsigned short><<<dim3(DIM / 32, SEQ / 32, G), dim3(32, 32), 0, stream>>>(
        Vb, 3 * DIM, (size_t)SEQ * 3 * DIM, Vt, SEQ, (size_t)DIM * SEQ);
    gemm8<256, EPI_F32><<<dim3(SEQ / 256, SEQ / 256, G), 512, 0, stream>>>(
        Qb, 3 * DIM, (size_t)SEQ * 3 * DIM, Kb, 3 * DIM, (size_t)SEQ * 3 * DIM,
        Sc, SEQ, (size_t)SEQ * SEQ, nullptr, DIM);
    softmax_kernel<<<dim3(SEQ, G), 256, 0, stream>>>(Sc, (size_t)SEQ * SEQ);
    gemm8<128, EPI_BF16><<<dim3(DIM / 128, SEQ / 256, G), 512, 0, stream>>>(
        (const unsigned short*)Sc, 2 * SEQ, (size_t)2 * SEQ * SEQ,
        Vt, SEQ, (size_t)DIM * SEQ,
        O + (size_t)b0 * SEQ * DIM, DIM, (size_t)SEQ * DIM, nullptr, SEQ);
  }
  gemm8<128, EPI_BIAS_F32><<<dim3(DIM / 128, ROWS / 256, 1), 512, 0, stream>>>(
      O, DIM, 0, WoutT, DIM, 0, out, DIM, 0, b_out, DIM);
}